// Round 1
// baseline (2806.405 us; speedup 1.0000x reference)
//
#include <hip/hip_runtime.h>
#include <math.h>

#define NN 100000
#define NE 640000

// ---------------- aggregation ----------------

__global__ __launch_bounds__(256) void k_count(const int* __restrict__ dst,
                                               float* __restrict__ cnt) {
    int e = blockIdx.x * 256 + threadIdx.x;
    if (e < NE) atomicAdd(&cnt[dst[e]], 1.0f);
}

// one edge per 32-lane group, float4 per lane (128 floats/row)
__global__ __launch_bounds__(256) void k_scatter128(const float* __restrict__ feat,
        const int* __restrict__ src, const int* __restrict__ dst,
        float* __restrict__ agg) {
    int tid = blockIdx.x * 256 + threadIdx.x;
    int e = tid >> 5;
    if (e >= NE) return;
    int c = (tid & 31) << 2;
    int s = src[e], d = dst[e];
    float4 v = *(const float4*)(feat + (size_t)s * 128 + c);
    float* p = agg + (size_t)d * 128 + c;
    atomicAdd(p + 0, v.x);
    atomicAdd(p + 1, v.y);
    atomicAdd(p + 2, v.z);
    atomicAdd(p + 3, v.w);
}

__global__ __launch_bounds__(256) void k_scatter2(const float* __restrict__ feat,
        const int* __restrict__ src, const int* __restrict__ dst,
        float* __restrict__ agg) {
    int e = blockIdx.x * 256 + threadIdx.x;
    if (e >= NE) return;
    int s = src[e], d = dst[e];
    atomicAdd(&agg[2 * d], feat[2 * s]);
    atomicAdd(&agg[2 * d + 1], feat[2 * s + 1]);
}

// ---------------- layer 1 fused: h1 = relu(norm(agg*inv @ W1l^T + x @ W1r^T + b1)) ----
// block: 256 threads = 4 (tr) x 64 (tc); BM=16 nodes, N=256, K=128, BK=16, TM=TN=4

__global__ __launch_bounds__(256) void k_layer1(const float* __restrict__ agg,
        const float* __restrict__ x, const float* __restrict__ W1l,
        const float* __restrict__ W1r, const float* __restrict__ b1,
        const float* __restrict__ cnt, float* __restrict__ h1) {
    __shared__ float sA[16][20];
    __shared__ float sX[16][20];
    __shared__ float sWl[16][256];
    __shared__ float sWr[16][256];
    int t = threadIdx.x;
    int tc = t & 63, tr = t >> 6;
    int r0 = blockIdx.x * 16;
    float accl[4][4] = {{0.f}}, accr[4][4] = {{0.f}};
    int kk = t & 15, m = t >> 4;   // for A-tile loads
    for (int k0 = 0; k0 < 128; k0 += 16) {
        sA[kk][m] = agg[(size_t)(r0 + m) * 128 + k0 + kk];
        sX[kk][m] = x[(size_t)(r0 + m) * 128 + k0 + kk];
        const float4* pl = (const float4*)(W1l + (size_t)t * 128 + k0);
        const float4* pr = (const float4*)(W1r + (size_t)t * 128 + k0);
        #pragma unroll
        for (int q = 0; q < 4; q++) {
            float4 vl = pl[q], vr = pr[q];
            sWl[4*q+0][t] = vl.x; sWl[4*q+1][t] = vl.y;
            sWl[4*q+2][t] = vl.z; sWl[4*q+3][t] = vl.w;
            sWr[4*q+0][t] = vr.x; sWr[4*q+1][t] = vr.y;
            sWr[4*q+2][t] = vr.z; sWr[4*q+3][t] = vr.w;
        }
        __syncthreads();
        #pragma unroll
        for (int k2 = 0; k2 < 16; k2++) {
            float4 al = *(const float4*)&sA[k2][4*tr];
            float4 ax = *(const float4*)&sX[k2][4*tr];
            float4 wl = *(const float4*)&sWl[k2][4*tc];
            float4 wr = *(const float4*)&sWr[k2][4*tc];
            float am[4] = {al.x, al.y, al.z, al.w};
            float xm[4] = {ax.x, ax.y, ax.z, ax.w};
            float wlv[4] = {wl.x, wl.y, wl.z, wl.w};
            float wrv[4] = {wr.x, wr.y, wr.z, wr.w};
            #pragma unroll
            for (int mm = 0; mm < 4; mm++)
                #pragma unroll
                for (int nn = 0; nn < 4; nn++) {
                    accl[mm][nn] += am[mm] * wlv[nn];
                    accr[mm][nn] += xm[mm] * wrv[nn];
                }
        }
        __syncthreads();
    }
    float4 bv = *(const float4*)(b1 + 4 * tc);
    float bn[4] = {bv.x, bv.y, bv.z, bv.w};
    #pragma unroll
    for (int mm = 0; mm < 4; mm++) {
        int node = r0 + 4 * tr + mm;
        float iv = 1.0f / fmaxf(cnt[node], 1.0f);
        float v[4]; float s = 0.f;
        #pragma unroll
        for (int nn = 0; nn < 4; nn++) {
            v[nn] = accl[mm][nn] * iv + accr[mm][nn] + bn[nn];
            s += v[nn] * v[nn];
        }
        // all 64 lanes of this wave share tr -> full-wave reduce over tc
        #pragma unroll
        for (int off = 32; off > 0; off >>= 1) s += __shfl_xor(s, off, 64);
        float invn = 1.0f / fmaxf(sqrtf(s), 1e-12f);
        float4 o;
        o.x = fmaxf(v[0] * invn, 0.f); o.y = fmaxf(v[1] * invn, 0.f);
        o.z = fmaxf(v[2] * invn, 0.f); o.w = fmaxf(v[3] * invn, 0.f);
        *(float4*)&h1[(size_t)node * 256 + 4 * tc] = o;
    }
}

// ---------------- layer 2 GEMM: p2 = h1 @ W2l^T  (M x 256) @ (128 x 256)^T ------
// block: 256 threads = 8 (tr) x 32 (tc); BM=32, N=128, K=256, BK=16, TM=TN=4

__global__ __launch_bounds__(256) void k_gemm_l2l(const float* __restrict__ A,
        const float* __restrict__ W, float* __restrict__ C) {
    __shared__ float sA[16][36];
    __shared__ float sW[16][128];
    int t = threadIdx.x;
    int tc = t & 31, tr = t >> 5;
    int r0 = blockIdx.x * 32;
    float acc[4][4] = {{0.f}};
    int kk = t & 15, mb = t >> 4;           // A loads
    int j = t & 127, kb = (t >> 7) * 8;     // W loads
    for (int k0 = 0; k0 < 256; k0 += 16) {
        sA[kk][mb]      = A[(size_t)(r0 + mb) * 256 + k0 + kk];
        sA[kk][mb + 16] = A[(size_t)(r0 + mb + 16) * 256 + k0 + kk];
        const float4* pw = (const float4*)(W + (size_t)j * 256 + k0 + kb);
        float4 w0 = pw[0], w1 = pw[1];
        sW[kb+0][j] = w0.x; sW[kb+1][j] = w0.y; sW[kb+2][j] = w0.z; sW[kb+3][j] = w0.w;
        sW[kb+4][j] = w1.x; sW[kb+5][j] = w1.y; sW[kb+6][j] = w1.z; sW[kb+7][j] = w1.w;
        __syncthreads();
        #pragma unroll
        for (int k2 = 0; k2 < 16; k2++) {
            float4 a = *(const float4*)&sA[k2][4*tr];
            float4 w = *(const float4*)&sW[k2][4*tc];
            float am[4] = {a.x, a.y, a.z, a.w};
            float wv[4] = {w.x, w.y, w.z, w.w};
            #pragma unroll
            for (int mm = 0; mm < 4; mm++)
                #pragma unroll
                for (int nn = 0; nn < 4; nn++)
                    acc[mm][nn] += am[mm] * wv[nn];
        }
        __syncthreads();
    }
    #pragma unroll
    for (int mm = 0; mm < 4; mm++) {
        int node = r0 + 4 * tr + mm;
        float4 o; o.x = acc[mm][0]; o.y = acc[mm][1]; o.z = acc[mm][2]; o.w = acc[mm][3];
        *(float4*)&C[(size_t)node * 128 + 4 * tc] = o;
    }
}

// ---------------- layer 2 epilogue: h2 = relu(norm(aggB*inv + h1 @ W2r^T + b2)) ---

__global__ __launch_bounds__(256) void k_layer2_ep(const float* __restrict__ A,
        const float* __restrict__ W, const float* __restrict__ aggB,
        const float* __restrict__ b2, const float* __restrict__ cnt,
        float* __restrict__ h2) {
    __shared__ float sA[16][36];
    __shared__ float sW[16][128];
    int t = threadIdx.x;
    int tc = t & 31, tr = t >> 5;
    int r0 = blockIdx.x * 32;
    float acc[4][4] = {{0.f}};
    int kk = t & 15, mb = t >> 4;
    int j = t & 127, kb = (t >> 7) * 8;
    for (int k0 = 0; k0 < 256; k0 += 16) {
        sA[kk][mb]      = A[(size_t)(r0 + mb) * 256 + k0 + kk];
        sA[kk][mb + 16] = A[(size_t)(r0 + mb + 16) * 256 + k0 + kk];
        const float4* pw = (const float4*)(W + (size_t)j * 256 + k0 + kb);
        float4 w0 = pw[0], w1 = pw[1];
        sW[kb+0][j] = w0.x; sW[kb+1][j] = w0.y; sW[kb+2][j] = w0.z; sW[kb+3][j] = w0.w;
        sW[kb+4][j] = w1.x; sW[kb+5][j] = w1.y; sW[kb+6][j] = w1.z; sW[kb+7][j] = w1.w;
        __syncthreads();
        #pragma unroll
        for (int k2 = 0; k2 < 16; k2++) {
            float4 a = *(const float4*)&sA[k2][4*tr];
            float4 w = *(const float4*)&sW[k2][4*tc];
            float am[4] = {a.x, a.y, a.z, a.w};
            float wv[4] = {w.x, w.y, w.z, w.w};
            #pragma unroll
            for (int mm = 0; mm < 4; mm++)
                #pragma unroll
                for (int nn = 0; nn < 4; nn++)
                    acc[mm][nn] += am[mm] * wv[nn];
        }
        __syncthreads();
    }
    float4 bv = *(const float4*)(b2 + 4 * tc);
    float bn[4] = {bv.x, bv.y, bv.z, bv.w};
    #pragma unroll
    for (int mm = 0; mm < 4; mm++) {
        int node = r0 + 4 * tr + mm;
        float iv = 1.0f / fmaxf(cnt[node], 1.0f);
        float4 ag = *(const float4*)&aggB[(size_t)node * 128 + 4 * tc];
        float agv[4] = {ag.x, ag.y, ag.z, ag.w};
        float v[4]; float s = 0.f;
        #pragma unroll
        for (int nn = 0; nn < 4; nn++) {
            v[nn] = acc[mm][nn] + agv[nn] * iv + bn[nn];
            s += v[nn] * v[nn];
        }
        // 32 lanes (same tr) are contiguous within the wave
        #pragma unroll
        for (int off = 16; off > 0; off >>= 1) s += __shfl_xor(s, off, 64);
        float invn = 1.0f / fmaxf(sqrtf(s), 1e-12f);
        float4 o;
        o.x = fmaxf(v[0] * invn, 0.f); o.y = fmaxf(v[1] * invn, 0.f);
        o.z = fmaxf(v[2] * invn, 0.f); o.w = fmaxf(v[3] * invn, 0.f);
        *(float4*)&h2[(size_t)node * 128 + 4 * tc] = o;
    }
}

// ---------------- layer 3 ----------------

__global__ __launch_bounds__(256) void k_q3(const float* __restrict__ h2,
        const float* __restrict__ W3l, float* __restrict__ q3) {
    __shared__ float sw[256];
    int t = threadIdx.x;
    sw[t] = W3l[t];
    __syncthreads();
    int i = blockIdx.x * 256 + t;
    if (i >= NN) return;
    const float4* row = (const float4*)(h2 + (size_t)i * 128);
    float a0 = 0.f, a1 = 0.f;
    #pragma unroll
    for (int q = 0; q < 32; q++) {
        float4 v = row[q];
        a0 += v.x * sw[4*q] + v.y * sw[4*q+1] + v.z * sw[4*q+2] + v.w * sw[4*q+3];
        a1 += v.x * sw[128+4*q] + v.y * sw[129+4*q] + v.z * sw[130+4*q] + v.w * sw[131+4*q];
    }
    q3[2 * i] = a0;
    q3[2 * i + 1] = a1;
}

__global__ __launch_bounds__(256) void k_final(const float* __restrict__ h2,
        const float* __restrict__ W3r, const float* __restrict__ b3,
        const float* __restrict__ aggq, const float* __restrict__ cnt,
        float* __restrict__ out) {
    __shared__ float sw[256];
    int t = threadIdx.x;
    sw[t] = W3r[t];
    __syncthreads();
    int i = blockIdx.x * 256 + t;
    if (i >= NN) return;
    const float4* row = (const float4*)(h2 + (size_t)i * 128);
    float a0 = 0.f, a1 = 0.f;
    #pragma unroll
    for (int q = 0; q < 32; q++) {
        float4 v = row[q];
        a0 += v.x * sw[4*q] + v.y * sw[4*q+1] + v.z * sw[4*q+2] + v.w * sw[4*q+3];
        a1 += v.x * sw[128+4*q] + v.y * sw[129+4*q] + v.z * sw[130+4*q] + v.w * sw[131+4*q];
    }
    float iv = 1.0f / fmaxf(cnt[i], 1.0f);
    float v0 = aggq[2 * i] * iv + a0 + b3[0];
    float v1 = aggq[2 * i + 1] * iv + a1 + b3[1];
    float invn = 1.0f / fmaxf(sqrtf(v0 * v0 + v1 * v1), 1e-12f);
    v0 *= invn; v1 *= invn;
    float mx = fmaxf(v0, v1);
    float l = logf(expf(v0 - mx) + expf(v1 - mx));
    out[2 * i] = v0 - mx - l;
    out[2 * i + 1] = v1 - mx - l;
}

// ---------------- launch ----------------

extern "C" void kernel_launch(void* const* d_in, const int* in_sizes, int n_in,
                              void* d_out, int out_size, void* d_ws, size_t ws_size,
                              hipStream_t stream) {
    const float* x   = (const float*)d_in[0];
    const int*   ei  = (const int*)d_in[1];
    const float* W1l = (const float*)d_in[2];
    const float* W1r = (const float*)d_in[3];
    const float* b1  = (const float*)d_in[4];
    const float* W2l = (const float*)d_in[5];
    const float* W2r = (const float*)d_in[6];
    const float* b2  = (const float*)d_in[7];
    const float* W3l = (const float*)d_in[8];
    const float* W3r = (const float*)d_in[9];
    const float* b3  = (const float*)d_in[10];
    float* out = (float*)d_out;
    const int* src = ei;
    const int* dst = ei + NE;

    float* ws   = (float*)d_ws;
    float* cnt  = ws;                       // 100000 (pad to 102400)
    float* aggA = ws + 102400;              // 12.8M floats (reused for L2 agg)
    float* h1   = aggA + 12800000;          // 25.6M floats
    float* p2   = h1 + 25600000;            // 12.8M floats (reused as h2)
    float* q3   = p2 + 12800000;            // 200000
    float* aggq = q3 + 200000;              // 200000
    // total ~51.7M floats = ~207 MB of d_ws

    hipMemsetAsync(cnt, 0, NN * sizeof(float), stream);
    hipMemsetAsync(aggA, 0, (size_t)NN * 128 * sizeof(float), stream);
    k_count<<<(NE + 255) / 256, 256, 0, stream>>>(dst, cnt);
    k_scatter128<<<(NE * 32) / 256, 256, 0, stream>>>(x, src, dst, aggA);
    k_layer1<<<NN / 16, 256, 0, stream>>>(aggA, x, W1l, W1r, b1, cnt, h1);

    k_gemm_l2l<<<NN / 32, 256, 0, stream>>>(h1, W2l, p2);
    hipMemsetAsync(aggA, 0, (size_t)NN * 128 * sizeof(float), stream);
    k_scatter128<<<(NE * 32) / 256, 256, 0, stream>>>(p2, src, dst, aggA);
    k_layer2_ep<<<NN / 32, 256, 0, stream>>>(h1, W2r, aggA, b2, cnt, p2 /*-> h2*/);
    float* h2 = p2;

    k_q3<<<(NN + 255) / 256, 256, 0, stream>>>(h2, W3l, q3);
    hipMemsetAsync(aggq, 0, (size_t)2 * NN * sizeof(float), stream);
    k_scatter2<<<(NE + 255) / 256, 256, 0, stream>>>(q3, src, dst, aggq);
    k_final<<<(NN + 255) / 256, 256, 0, stream>>>(h2, W3r, b3, aggq, cnt, out);
}

// Round 2
// 807.729 us; speedup vs baseline: 3.4744x; 3.4744x over previous
//
#include <hip/hip_runtime.h>
#include <math.h>

#define NN 100000
#define NE 640000

// ================= CSR build =================

__global__ __launch_bounds__(256) void k_hist(const int* __restrict__ dst,
                                              int* __restrict__ deg) {
    int e = blockIdx.x * 256 + threadIdx.x;
    if (e < NE) atomicAdd(&deg[dst[e]], 1);
}

// single-block exclusive scan of deg[0..NN) -> rowptr, cursor; rowptr[NN]=NE
__global__ __launch_bounds__(1024) void k_scan(const int* __restrict__ deg,
        int* __restrict__ rowptr, int* __restrict__ cursor) {
    __shared__ int wsum[16];
    __shared__ int woff[16];
    int t = threadIdx.x;
    int lane = t & 63, wid = t >> 6;
    int carry = 0;
    for (int base = 0; base < NN; base += 1024) {
        int i = base + t;
        int v = (i < NN) ? deg[i] : 0;
        // inclusive scan within 64-lane wave
        int s = v;
        #pragma unroll
        for (int off = 1; off < 64; off <<= 1) {
            int u = __shfl_up(s, off, 64);
            if (lane >= off) s += u;
        }
        if (lane == 63) wsum[wid] = s;
        __syncthreads();
        if (wid == 0) {
            int ws = (lane < 16) ? wsum[lane] : 0;
            #pragma unroll
            for (int off = 1; off < 16; off <<= 1) {
                int u = __shfl_up(ws, off, 64);
                if (lane >= off) ws += u;
            }
            if (lane < 16) woff[lane] = ws;
        }
        __syncthreads();
        int excl = carry + (s - v) + (wid ? woff[wid - 1] : 0);
        if (i < NN) { rowptr[i] = excl; cursor[i] = excl; }
        carry += woff[15];
        __syncthreads();   // protect wsum/woff before next chunk overwrites
    }
    if (t == 0) rowptr[NN] = carry;
}

__global__ __launch_bounds__(256) void k_fill(const int* __restrict__ src,
        const int* __restrict__ dst, int* __restrict__ cursor,
        int* __restrict__ csr) {
    int e = blockIdx.x * 256 + threadIdx.x;
    if (e >= NE) return;
    int p = atomicAdd(&cursor[dst[e]], 1);
    csr[p] = src[e];
}

// ================= gather-mean aggregation =================

// one node per 32-lane group; lane covers one float4 column (128 floats/row)
__global__ __launch_bounds__(256) void k_gather128(const float* __restrict__ feat,
        const int* __restrict__ rowptr, const int* __restrict__ csr,
        float* __restrict__ agg) {
    int tid = blockIdx.x * 256 + threadIdx.x;
    int node = tid >> 5;
    if (node >= NN) return;
    int lane4 = (tid & 31) << 2;
    int beg = rowptr[node], end = rowptr[node + 1];
    float4 acc = make_float4(0.f, 0.f, 0.f, 0.f);
    int e = beg;
    for (; e + 1 < end; e += 2) {
        int s0 = csr[e], s1 = csr[e + 1];
        float4 v0 = *(const float4*)(feat + (size_t)s0 * 128 + lane4);
        float4 v1 = *(const float4*)(feat + (size_t)s1 * 128 + lane4);
        acc.x += v0.x + v1.x; acc.y += v0.y + v1.y;
        acc.z += v0.z + v1.z; acc.w += v0.w + v1.w;
    }
    if (e < end) {
        int s0 = csr[e];
        float4 v0 = *(const float4*)(feat + (size_t)s0 * 128 + lane4);
        acc.x += v0.x; acc.y += v0.y; acc.z += v0.z; acc.w += v0.w;
    }
    float iv = 1.0f / (float)max(end - beg, 1);
    acc.x *= iv; acc.y *= iv; acc.z *= iv; acc.w *= iv;
    *(float4*)(agg + (size_t)node * 128 + lane4) = acc;
}

// 2-wide gather-mean (layer 3, post-projection)
__global__ __launch_bounds__(256) void k_gather2(const float* __restrict__ feat,
        const int* __restrict__ rowptr, const int* __restrict__ csr,
        float* __restrict__ agg) {
    int n = blockIdx.x * 256 + threadIdx.x;
    if (n >= NN) return;
    int beg = rowptr[n], end = rowptr[n + 1];
    float a0 = 0.f, a1 = 0.f;
    for (int e = beg; e < end; e++) {
        int s = csr[e];
        a0 += feat[2 * s];
        a1 += feat[2 * s + 1];
    }
    float iv = 1.0f / (float)max(end - beg, 1);
    agg[2 * n] = a0 * iv;
    agg[2 * n + 1] = a1 * iv;
}

// ================= layer 1 fused =================
// h1 = relu(norm(aggMean @ W1l^T + x @ W1r^T + b1))
// block: 256 threads = 4 (tr) x 64 (tc); BM=16, N=256, K=128, BK=16, TM=TN=4

__global__ __launch_bounds__(256) void k_layer1(const float* __restrict__ agg,
        const float* __restrict__ x, const float* __restrict__ W1l,
        const float* __restrict__ W1r, const float* __restrict__ b1,
        float* __restrict__ h1) {
    __shared__ float sA[16][20];
    __shared__ float sX[16][20];
    __shared__ float sWl[16][256];
    __shared__ float sWr[16][256];
    int t = threadIdx.x;
    int tc = t & 63, tr = t >> 6;
    int r0 = blockIdx.x * 16;
    float accl[4][4] = {{0.f}}, accr[4][4] = {{0.f}};
    int kk = t & 15, m = t >> 4;
    for (int k0 = 0; k0 < 128; k0 += 16) {
        sA[kk][m] = agg[(size_t)(r0 + m) * 128 + k0 + kk];
        sX[kk][m] = x[(size_t)(r0 + m) * 128 + k0 + kk];
        const float4* pl = (const float4*)(W1l + (size_t)t * 128 + k0);
        const float4* pr = (const float4*)(W1r + (size_t)t * 128 + k0);
        #pragma unroll
        for (int q = 0; q < 4; q++) {
            float4 vl = pl[q], vr = pr[q];
            sWl[4*q+0][t] = vl.x; sWl[4*q+1][t] = vl.y;
            sWl[4*q+2][t] = vl.z; sWl[4*q+3][t] = vl.w;
            sWr[4*q+0][t] = vr.x; sWr[4*q+1][t] = vr.y;
            sWr[4*q+2][t] = vr.z; sWr[4*q+3][t] = vr.w;
        }
        __syncthreads();
        #pragma unroll
        for (int k2 = 0; k2 < 16; k2++) {
            float4 al = *(const float4*)&sA[k2][4*tr];
            float4 ax = *(const float4*)&sX[k2][4*tr];
            float4 wl = *(const float4*)&sWl[k2][4*tc];
            float4 wr = *(const float4*)&sWr[k2][4*tc];
            float am[4] = {al.x, al.y, al.z, al.w};
            float xm[4] = {ax.x, ax.y, ax.z, ax.w};
            float wlv[4] = {wl.x, wl.y, wl.z, wl.w};
            float wrv[4] = {wr.x, wr.y, wr.z, wr.w};
            #pragma unroll
            for (int mm = 0; mm < 4; mm++)
                #pragma unroll
                for (int nn = 0; nn < 4; nn++) {
                    accl[mm][nn] += am[mm] * wlv[nn];
                    accr[mm][nn] += xm[mm] * wrv[nn];
                }
        }
        __syncthreads();
    }
    float4 bv = *(const float4*)(b1 + 4 * tc);
    float bn[4] = {bv.x, bv.y, bv.z, bv.w};
    #pragma unroll
    for (int mm = 0; mm < 4; mm++) {
        int node = r0 + 4 * tr + mm;
        float v[4]; float s = 0.f;
        #pragma unroll
        for (int nn = 0; nn < 4; nn++) {
            v[nn] = accl[mm][nn] + accr[mm][nn] + bn[nn];
            s += v[nn] * v[nn];
        }
        #pragma unroll
        for (int off = 32; off > 0; off >>= 1) s += __shfl_xor(s, off, 64);
        float invn = 1.0f / fmaxf(sqrtf(s), 1e-12f);
        float4 o;
        o.x = fmaxf(v[0] * invn, 0.f); o.y = fmaxf(v[1] * invn, 0.f);
        o.z = fmaxf(v[2] * invn, 0.f); o.w = fmaxf(v[3] * invn, 0.f);
        *(float4*)&h1[(size_t)node * 256 + 4 * tc] = o;
    }
}

// ================= layer 2 GEMM: p2 = h1 @ W2l^T =================
// block: 256 = 8 (tr) x 32 (tc); BM=32, N=128, K=256, BK=16, TM=TN=4

__global__ __launch_bounds__(256) void k_gemm_l2l(const float* __restrict__ A,
        const float* __restrict__ W, float* __restrict__ C) {
    __shared__ float sA[16][36];
    __shared__ float sW[16][128];
    int t = threadIdx.x;
    int tc = t & 31, tr = t >> 5;
    int r0 = blockIdx.x * 32;
    float acc[4][4] = {{0.f}};
    int kk = t & 15, mb = t >> 4;
    int j = t & 127, kb = (t >> 7) * 8;
    for (int k0 = 0; k0 < 256; k0 += 16) {
        sA[kk][mb]      = A[(size_t)(r0 + mb) * 256 + k0 + kk];
        sA[kk][mb + 16] = A[(size_t)(r0 + mb + 16) * 256 + k0 + kk];
        const float4* pw = (const float4*)(W + (size_t)j * 256 + k0 + kb);
        float4 w0 = pw[0], w1 = pw[1];
        sW[kb+0][j] = w0.x; sW[kb+1][j] = w0.y; sW[kb+2][j] = w0.z; sW[kb+3][j] = w0.w;
        sW[kb+4][j] = w1.x; sW[kb+5][j] = w1.y; sW[kb+6][j] = w1.z; sW[kb+7][j] = w1.w;
        __syncthreads();
        #pragma unroll
        for (int k2 = 0; k2 < 16; k2++) {
            float4 a = *(const float4*)&sA[k2][4*tr];
            float4 w = *(const float4*)&sW[k2][4*tc];
            float am[4] = {a.x, a.y, a.z, a.w};
            float wv[4] = {w.x, w.y, w.z, w.w};
            #pragma unroll
            for (int mm = 0; mm < 4; mm++)
                #pragma unroll
                for (int nn = 0; nn < 4; nn++)
                    acc[mm][nn] += am[mm] * wv[nn];
        }
        __syncthreads();
    }
    #pragma unroll
    for (int mm = 0; mm < 4; mm++) {
        int node = r0 + 4 * tr + mm;
        float4 o; o.x = acc[mm][0]; o.y = acc[mm][1]; o.z = acc[mm][2]; o.w = acc[mm][3];
        *(float4*)&C[(size_t)node * 128 + 4 * tc] = o;
    }
}

// ================= layer 2 epilogue =================
// h2 = relu(norm(aggMeanB + h1 @ W2r^T + b2))

__global__ __launch_bounds__(256) void k_layer2_ep(const float* __restrict__ A,
        const float* __restrict__ W, const float* __restrict__ aggB,
        const float* __restrict__ b2, float* __restrict__ h2) {
    __shared__ float sA[16][36];
    __shared__ float sW[16][128];
    int t = threadIdx.x;
    int tc = t & 31, tr = t >> 5;
    int r0 = blockIdx.x * 32;
    float acc[4][4] = {{0.f}};
    int kk = t & 15, mb = t >> 4;
    int j = t & 127, kb = (t >> 7) * 8;
    for (int k0 = 0; k0 < 256; k0 += 16) {
        sA[kk][mb]      = A[(size_t)(r0 + mb) * 256 + k0 + kk];
        sA[kk][mb + 16] = A[(size_t)(r0 + mb + 16) * 256 + k0 + kk];
        const float4* pw = (const float4*)(W + (size_t)j * 256 + k0 + kb);
        float4 w0 = pw[0], w1 = pw[1];
        sW[kb+0][j] = w0.x; sW[kb+1][j] = w0.y; sW[kb+2][j] = w0.z; sW[kb+3][j] = w0.w;
        sW[kb+4][j] = w1.x; sW[kb+5][j] = w1.y; sW[kb+6][j] = w1.z; sW[kb+7][j] = w1.w;
        __syncthreads();
        #pragma unroll
        for (int k2 = 0; k2 < 16; k2++) {
            float4 a = *(const float4*)&sA[k2][4*tr];
            float4 w = *(const float4*)&sW[k2][4*tc];
            float am[4] = {a.x, a.y, a.z, a.w};
            float wv[4] = {w.x, w.y, w.z, w.w};
            #pragma unroll
            for (int mm = 0; mm < 4; mm++)
                #pragma unroll
                for (int nn = 0; nn < 4; nn++)
                    acc[mm][nn] += am[mm] * wv[nn];
        }
        __syncthreads();
    }
    float4 bv = *(const float4*)(b2 + 4 * tc);
    float bn[4] = {bv.x, bv.y, bv.z, bv.w};
    #pragma unroll
    for (int mm = 0; mm < 4; mm++) {
        int node = r0 + 4 * tr + mm;
        float4 ag = *(const float4*)&aggB[(size_t)node * 128 + 4 * tc];
        float agv[4] = {ag.x, ag.y, ag.z, ag.w};
        float v[4]; float s = 0.f;
        #pragma unroll
        for (int nn = 0; nn < 4; nn++) {
            v[nn] = acc[mm][nn] + agv[nn] + bn[nn];
            s += v[nn] * v[nn];
        }
        #pragma unroll
        for (int off = 16; off > 0; off >>= 1) s += __shfl_xor(s, off, 64);
        float invn = 1.0f / fmaxf(sqrtf(s), 1e-12f);
        float4 o;
        o.x = fmaxf(v[0] * invn, 0.f); o.y = fmaxf(v[1] * invn, 0.f);
        o.z = fmaxf(v[2] * invn, 0.f); o.w = fmaxf(v[3] * invn, 0.f);
        *(float4*)&h2[(size_t)node * 128 + 4 * tc] = o;
    }
}

// ================= layer 3 =================

__global__ __launch_bounds__(256) void k_q3(const float* __restrict__ h2,
        const float* __restrict__ W3l, float* __restrict__ q3) {
    __shared__ float sw[256];
    int t = threadIdx.x;
    sw[t] = W3l[t];
    __syncthreads();
    int i = blockIdx.x * 256 + t;
    if (i >= NN) return;
    const float4* row = (const float4*)(h2 + (size_t)i * 128);
    float a0 = 0.f, a1 = 0.f;
    #pragma unroll
    for (int q = 0; q < 32; q++) {
        float4 v = row[q];
        a0 += v.x * sw[4*q] + v.y * sw[4*q+1] + v.z * sw[4*q+2] + v.w * sw[4*q+3];
        a1 += v.x * sw[128+4*q] + v.y * sw[129+4*q] + v.z * sw[130+4*q] + v.w * sw[131+4*q];
    }
    q3[2 * i] = a0;
    q3[2 * i + 1] = a1;
}

__global__ __launch_bounds__(256) void k_final(const float* __restrict__ h2,
        const float* __restrict__ W3r, const float* __restrict__ b3,
        const float* __restrict__ aggq, float* __restrict__ out) {
    __shared__ float sw[256];
    int t = threadIdx.x;
    sw[t] = W3r[t];
    __syncthreads();
    int i = blockIdx.x * 256 + t;
    if (i >= NN) return;
    const float4* row = (const float4*)(h2 + (size_t)i * 128);
    float a0 = 0.f, a1 = 0.f;
    #pragma unroll
    for (int q = 0; q < 32; q++) {
        float4 v = row[q];
        a0 += v.x * sw[4*q] + v.y * sw[4*q+1] + v.z * sw[4*q+2] + v.w * sw[4*q+3];
        a1 += v.x * sw[128+4*q] + v.y * sw[129+4*q] + v.z * sw[130+4*q] + v.w * sw[131+4*q];
    }
    float v0 = aggq[2 * i] + a0 + b3[0];
    float v1 = aggq[2 * i + 1] + a1 + b3[1];
    float invn = 1.0f / fmaxf(sqrtf(v0 * v0 + v1 * v1), 1e-12f);
    v0 *= invn; v1 *= invn;
    float mx = fmaxf(v0, v1);
    float l = logf(expf(v0 - mx) + expf(v1 - mx));
    out[2 * i] = v0 - mx - l;
    out[2 * i + 1] = v1 - mx - l;
}

// ================= launch =================

extern "C" void kernel_launch(void* const* d_in, const int* in_sizes, int n_in,
                              void* d_out, int out_size, void* d_ws, size_t ws_size,
                              hipStream_t stream) {
    const float* x   = (const float*)d_in[0];
    const int*   ei  = (const int*)d_in[1];
    const float* W1l = (const float*)d_in[2];
    const float* W1r = (const float*)d_in[3];
    const float* b1  = (const float*)d_in[4];
    const float* W2l = (const float*)d_in[5];
    const float* W2r = (const float*)d_in[6];
    const float* b2  = (const float*)d_in[7];
    const float* W3l = (const float*)d_in[8];
    const float* W3r = (const float*)d_in[9];
    const float* b3  = (const float*)d_in[10];
    float* out = (float*)d_out;
    const int* src = ei;
    const int* dst = ei + NE;

    int* deg    = (int*)d_ws;               // 102400
    int* rowptr = deg + 102400;             // 102400 (NN+1 fits)
    int* cursor = rowptr + 102400;          // 102400
    int* csr    = cursor + 102400;          // 655360
    float* aggA = (float*)(csr + 655360);   // 12.8M floats (reused for L2 agg)
    float* h1   = aggA + 12800000;          // 25.6M
    float* p2   = h1 + 25600000;            // 12.8M (reused as h2)
    float* q3   = p2 + 12800000;            // 200000
    float* aggq = q3 + 200000;              // 200000

    // --- CSR build ---
    hipMemsetAsync(deg, 0, NN * sizeof(int), stream);
    k_hist<<<(NE + 255) / 256, 256, 0, stream>>>(dst, deg);
    k_scan<<<1, 1024, 0, stream>>>(deg, rowptr, cursor);
    k_fill<<<(NE + 255) / 256, 256, 0, stream>>>(src, dst, cursor, csr);

    // --- layer 1 ---
    k_gather128<<<(NN * 32 + 255) / 256, 256, 0, stream>>>(x, rowptr, csr, aggA);
    k_layer1<<<NN / 16, 256, 0, stream>>>(aggA, x, W1l, W1r, b1, h1);

    // --- layer 2 (project-then-aggregate) ---
    k_gemm_l2l<<<NN / 32, 256, 0, stream>>>(h1, W2l, p2);
    k_gather128<<<(NN * 32 + 255) / 256, 256, 0, stream>>>(p2, rowptr, csr, aggA);
    k_layer2_ep<<<NN / 32, 256, 0, stream>>>(h1, W2r, aggA, b2, p2 /*-> h2*/);
    float* h2 = p2;

    // --- layer 3 (project-then-aggregate, dim 2) ---
    k_q3<<<(NN + 255) / 256, 256, 0, stream>>>(h2, W3l, q3);
    k_gather2<<<(NN + 255) / 256, 256, 0, stream>>>(q3, rowptr, csr, aggq);
    k_final<<<(NN + 255) / 256, 256, 0, stream>>>(h2, W3r, b3, aggq, out);
}

// Round 4
// 548.349 us; speedup vs baseline: 5.1179x; 1.4730x over previous
//
#include <hip/hip_runtime.h>
#include <math.h>

#define NN 100000
#define NE 640000
#define MPAD 100032   // NN rounded up to 64

typedef __bf16 bf16_t;
typedef bf16_t bf16x8 __attribute__((ext_vector_type(8)));
typedef float  f32x4  __attribute__((ext_vector_type(4)));

// ================= CSR build =================

__global__ __launch_bounds__(256) void k_hist(const int* __restrict__ dst,
                                              int* __restrict__ deg) {
    int e = blockIdx.x * 256 + threadIdx.x;
    if (e < NE) atomicAdd(&deg[dst[e]], 1);
}

__global__ __launch_bounds__(1024) void k_scan(const int* __restrict__ deg,
        int* __restrict__ rowptr, int* __restrict__ cursor) {
    __shared__ int wsum[16];
    __shared__ int woff[16];
    int t = threadIdx.x;
    int lane = t & 63, wid = t >> 6;
    int carry = 0;
    for (int base = 0; base < NN; base += 1024) {
        int i = base + t;
        int v = (i < NN) ? deg[i] : 0;
        int s = v;
        #pragma unroll
        for (int off = 1; off < 64; off <<= 1) {
            int u = __shfl_up(s, off, 64);
            if (lane >= off) s += u;
        }
        if (lane == 63) wsum[wid] = s;
        __syncthreads();
        if (wid == 0) {
            int ws = (lane < 16) ? wsum[lane] : 0;
            #pragma unroll
            for (int off = 1; off < 16; off <<= 1) {
                int u = __shfl_up(ws, off, 64);
                if (lane >= off) ws += u;
            }
            if (lane < 16) woff[lane] = ws;
        }
        __syncthreads();
        int excl = carry + (s - v) + (wid ? woff[wid - 1] : 0);
        if (i < NN) { rowptr[i] = excl; cursor[i] = excl; }
        carry += woff[15];
        __syncthreads();
    }
    if (t == 0) rowptr[NN] = carry;
}

__global__ __launch_bounds__(256) void k_fill(const int* __restrict__ src,
        const int* __restrict__ dst, int* __restrict__ cursor,
        int* __restrict__ csr) {
    int e = blockIdx.x * 256 + threadIdx.x;
    if (e >= NE) return;
    int p = atomicAdd(&cursor[dst[e]], 1);
    csr[p] = src[e];
}

// ================= weight split (f32 -> hi/lo bf16) =================

// W1cat[j] = [W1l[j,0:128] | W1r[j,0:128]]  (256x256)
__global__ __launch_bounds__(256) void k_split_w1(const float* __restrict__ W1l,
        const float* __restrict__ W1r, bf16_t* __restrict__ Wh,
        bf16_t* __restrict__ Wl) {
    int j = blockIdx.x, t = threadIdx.x;
    float f = (t < 128) ? W1l[j * 128 + t] : W1r[j * 128 + (t - 128)];
    bf16_t h = (bf16_t)f;
    bf16_t l = (bf16_t)(f - (float)h);
    Wh[j * 256 + t] = h;
    Wl[j * 256 + t] = l;
}

// W2cat rows 0..127 = W2l, rows 128..255 = W2r  (256x256)
__global__ __launch_bounds__(256) void k_split_w2(const float* __restrict__ W2l,
        const float* __restrict__ W2r, bf16_t* __restrict__ Wh,
        bf16_t* __restrict__ Wl) {
    int j = blockIdx.x, t = threadIdx.x;
    float f = (j < 128) ? W2l[j * 256 + t] : W2r[(j - 128) * 256 + t];
    bf16_t h = (bf16_t)f;
    bf16_t l = (bf16_t)(f - (float)h);
    Wh[j * 256 + t] = h;
    Wl[j * 256 + t] = l;
}

// ================= gather-mean (f32, 128 wide, strided) =================
// one node per 32-lane group; lane covers one float4 column

__global__ __launch_bounds__(256) void k_gather128s(const float* __restrict__ feat,
        int fstride, const int* __restrict__ rowptr, const int* __restrict__ csr,
        float* __restrict__ agg, int astride) {
    int tid = blockIdx.x * 256 + threadIdx.x;
    int node = tid >> 5;
    if (node >= NN) return;
    int lane4 = (tid & 31) << 2;
    int beg = rowptr[node], end = rowptr[node + 1];
    float4 acc = make_float4(0.f, 0.f, 0.f, 0.f);
    int e = beg;
    for (; e + 1 < end; e += 2) {
        int s0 = csr[e], s1 = csr[e + 1];
        float4 v0 = *(const float4*)(feat + (size_t)s0 * fstride + lane4);
        float4 v1 = *(const float4*)(feat + (size_t)s1 * fstride + lane4);
        acc.x += v0.x + v1.x; acc.y += v0.y + v1.y;
        acc.z += v0.z + v1.z; acc.w += v0.w + v1.w;
    }
    if (e < end) {
        int s0 = csr[e];
        float4 v0 = *(const float4*)(feat + (size_t)s0 * fstride + lane4);
        acc.x += v0.x; acc.y += v0.y; acc.z += v0.z; acc.w += v0.w;
    }
    float iv = 1.0f / (float)max(end - beg, 1);
    acc.x *= iv; acc.y *= iv; acc.z *= iv; acc.w *= iv;
    *(float4*)(agg + (size_t)node * astride + lane4) = acc;
}

// 2-wide gather-mean (layer 3, f32)
__global__ __launch_bounds__(256) void k_gather2(const float* __restrict__ feat,
        const int* __restrict__ rowptr, const int* __restrict__ csr,
        float* __restrict__ agg) {
    int n = blockIdx.x * 256 + threadIdx.x;
    if (n >= NN) return;
    int beg = rowptr[n], end = rowptr[n + 1];
    float a0 = 0.f, a1 = 0.f;
    for (int e = beg; e < end; e++) {
        int s = csr[e];
        a0 += feat[2 * s];
        a1 += feat[2 * s + 1];
    }
    float iv = 1.0f / (float)max(end - beg, 1);
    agg[2 * n] = a0 * iv;
    agg[2 * n + 1] = a1 * iv;
}

// ================= split-bf16 MFMA GEMM =================
// C[M x 256] = A[M x 256] @ W[256 x 256]^T with A,W f32 emulated as hi+lo bf16:
// C ~= Ah*Wh + Al*Wh + Ah*Wl   (error ~2^-17 rel)
// block 256 = 4 waves; BM=64, BN=256 (wave owns 64 cols), BK=32.
// frag layouts (HW-verified m89/m120): A/B lane = [idx=lane&15][k=quad*8+j];
// C/D: col=lane&15, row=quad*4+reg.

#define PADK 8

__device__ __forceinline__ void split8(const float* __restrict__ p,
                                       bf16x8& h, bf16x8& l) {
    float4 v0 = *(const float4*)p;
    float4 v1 = *(const float4*)(p + 4);
    float f[8] = {v0.x, v0.y, v0.z, v0.w, v1.x, v1.y, v1.z, v1.w};
    #pragma unroll
    for (int i = 0; i < 8; i++) {
        bf16_t hi = (bf16_t)f[i];
        h[i] = hi;
        l[i] = (bf16_t)(f[i] - (float)hi);
    }
}

// Layer-1 GEMM, A = [agg | x] (two f32 sources, each M x 128),
// fused epilogue: h1 = relu(l2norm(C + b1))
__global__ __launch_bounds__(256) void k_gemm_l1(const float* __restrict__ Aa,
        const float* __restrict__ Ax, const bf16_t* __restrict__ Wh,
        const bf16_t* __restrict__ Wl, const float* __restrict__ bias,
        float* __restrict__ H) {
    __shared__ bf16_t sAh[64][32 + PADK], sAl[64][32 + PADK];
    __shared__ bf16_t sWh[256][32 + PADK], sWl[256][32 + PADK];
    __shared__ float pr[64][4];
    int t = threadIdx.x;
    int wave = t >> 6, lane = t & 63, quad = lane >> 4, l16 = lane & 15;
    int r0 = blockIdx.x * 64;
    f32x4 acc[4][4] = {};
    int arow = t >> 2, aseg = t & 3;
    int grow = r0 + arow; if (grow >= NN) grow = NN - 1;   // clamp: avoid OOB on inputs
    for (int k0 = 0; k0 < 256; k0 += 32) {
        const float* Asrc = (k0 < 128) ? Aa : Ax;
        int kb = (k0 < 128) ? k0 : (k0 - 128);
        bf16x8 h8, l8;
        split8(&Asrc[(size_t)grow * 128 + kb + aseg * 8], h8, l8);
        *(bf16x8*)&sAh[arow][aseg * 8] = h8;
        *(bf16x8*)&sAl[arow][aseg * 8] = l8;
        #pragma unroll
        for (int i = 0; i < 4; i++) {
            int wr = arow + i * 64;
            *(bf16x8*)&sWh[wr][aseg * 8] = *(const bf16x8*)&Wh[(size_t)wr * 256 + k0 + aseg * 8];
            *(bf16x8*)&sWl[wr][aseg * 8] = *(const bf16x8*)&Wl[(size_t)wr * 256 + k0 + aseg * 8];
        }
        __syncthreads();
        bf16x8 ah[4], al[4], bh[4], bl[4];
        #pragma unroll
        for (int mt = 0; mt < 4; mt++) {
            ah[mt] = *(bf16x8*)&sAh[mt * 16 + l16][quad * 8];
            al[mt] = *(bf16x8*)&sAl[mt * 16 + l16][quad * 8];
        }
        #pragma unroll
        for (int nt = 0; nt < 4; nt++) {
            bh[nt] = *(bf16x8*)&sWh[wave * 64 + nt * 16 + l16][quad * 8];
            bl[nt] = *(bf16x8*)&sWl[wave * 64 + nt * 16 + l16][quad * 8];
        }
        #pragma unroll
        for (int mt = 0; mt < 4; mt++)
            #pragma unroll
            for (int nt = 0; nt < 4; nt++) {
                acc[mt][nt] = __builtin_amdgcn_mfma_f32_16x16x32_bf16(ah[mt], bh[nt], acc[mt][nt], 0, 0, 0);
                acc[mt][nt] = __builtin_amdgcn_mfma_f32_16x16x32_bf16(al[mt], bh[nt], acc[mt][nt], 0, 0, 0);
                acc[mt][nt] = __builtin_amdgcn_mfma_f32_16x16x32_bf16(ah[mt], bl[nt], acc[mt][nt], 0, 0, 0);
            }
        __syncthreads();
    }
    // ---- fused epilogue: bias, row L2-norm across 256 cols, relu ----
    float bcol[4];
    #pragma unroll
    for (int nt = 0; nt < 4; nt++) bcol[nt] = bias[wave * 64 + nt * 16 + l16];
    #pragma unroll
    for (int mt = 0; mt < 4; mt++)
        #pragma unroll
        for (int nt = 0; nt < 4; nt++)
            #pragma unroll
            for (int rg = 0; rg < 4; rg++)
                acc[mt][nt][rg] += bcol[nt];
    float ss[4][4];
    #pragma unroll
    for (int mt = 0; mt < 4; mt++)
        #pragma unroll
        for (int rg = 0; rg < 4; rg++) {
            float s = 0.f;
            #pragma unroll
            for (int nt = 0; nt < 4; nt++) s += acc[mt][nt][rg] * acc[mt][nt][rg];
            #pragma unroll
            for (int off = 1; off < 16; off <<= 1) s += __shfl_xor(s, off, 64);
            ss[mt][rg] = s;   // sum over this wave's 64 cols for row mt*16+quad*4+rg
        }
    if (l16 == 0) {
        #pragma unroll
        for (int mt = 0; mt < 4; mt++)
            #pragma unroll
            for (int rg = 0; rg < 4; rg++)
                pr[mt * 16 + quad * 4 + rg][wave] = ss[mt][rg];
    }
    __syncthreads();
    #pragma unroll
    for (int mt = 0; mt < 4; mt++)
        #pragma unroll
        for (int rg = 0; rg < 4; rg++) {
            int lr = mt * 16 + quad * 4 + rg;
            int row = r0 + lr;
            if (row >= NN) continue;
            float tot = pr[lr][0] + pr[lr][1] + pr[lr][2] + pr[lr][3];
            float inv = 1.0f / fmaxf(sqrtf(tot), 1e-12f);
            #pragma unroll
            for (int nt = 0; nt < 4; nt++) {
                int col = wave * 64 + nt * 16 + l16;
                H[(size_t)row * 256 + col] = fmaxf(acc[mt][nt][rg] * inv, 0.f);
            }
        }
}

// Layer-2 GEMM: C2 = h1 @ [W2l;W2r]^T, plain f32 store (norm needs agg first)
__global__ __launch_bounds__(256) void k_gemm_l2(const float* __restrict__ A,
        const bf16_t* __restrict__ Wh, const bf16_t* __restrict__ Wl,
        float* __restrict__ C) {
    __shared__ bf16_t sAh[64][32 + PADK], sAl[64][32 + PADK];
    __shared__ bf16_t sWh[256][32 + PADK], sWl[256][32 + PADK];
    int t = threadIdx.x;
    int wave = t >> 6, lane = t & 63, quad = lane >> 4, l16 = lane & 15;
    int r0 = blockIdx.x * 64;
    f32x4 acc[4][4] = {};
    int arow = t >> 2, aseg = t & 3;
    int grow = r0 + arow; if (grow >= NN) grow = NN - 1;
    for (int k0 = 0; k0 < 256; k0 += 32) {
        bf16x8 h8, l8;
        split8(&A[(size_t)grow * 256 + k0 + aseg * 8], h8, l8);
        *(bf16x8*)&sAh[arow][aseg * 8] = h8;
        *(bf16x8*)&sAl[arow][aseg * 8] = l8;
        #pragma unroll
        for (int i = 0; i < 4; i++) {
            int wr = arow + i * 64;
            *(bf16x8*)&sWh[wr][aseg * 8] = *(const bf16x8*)&Wh[(size_t)wr * 256 + k0 + aseg * 8];
            *(bf16x8*)&sWl[wr][aseg * 8] = *(const bf16x8*)&Wl[(size_t)wr * 256 + k0 + aseg * 8];
        }
        __syncthreads();
        bf16x8 ah[4], al[4], bh[4], bl[4];
        #pragma unroll
        for (int mt = 0; mt < 4; mt++) {
            ah[mt] = *(bf16x8*)&sAh[mt * 16 + l16][quad * 8];
            al[mt] = *(bf16x8*)&sAl[mt * 16 + l16][quad * 8];
        }
        #pragma unroll
        for (int nt = 0; nt < 4; nt++) {
            bh[nt] = *(bf16x8*)&sWh[wave * 64 + nt * 16 + l16][quad * 8];
            bl[nt] = *(bf16x8*)&sWl[wave * 64 + nt * 16 + l16][quad * 8];
        }
        #pragma unroll
        for (int mt = 0; mt < 4; mt++)
            #pragma unroll
            for (int nt = 0; nt < 4; nt++) {
                acc[mt][nt] = __builtin_amdgcn_mfma_f32_16x16x32_bf16(ah[mt], bh[nt], acc[mt][nt], 0, 0, 0);
                acc[mt][nt] = __builtin_amdgcn_mfma_f32_16x16x32_bf16(al[mt], bh[nt], acc[mt][nt], 0, 0, 0);
                acc[mt][nt] = __builtin_amdgcn_mfma_f32_16x16x32_bf16(ah[mt], bl[nt], acc[mt][nt], 0, 0, 0);
            }
        __syncthreads();
    }
    #pragma unroll
    for (int mt = 0; mt < 4; mt++)
        #pragma unroll
        for (int rg = 0; rg < 4; rg++) {
            int row = r0 + mt * 16 + quad * 4 + rg;
            if (row >= NN) continue;
            #pragma unroll
            for (int nt = 0; nt < 4; nt++) {
                int col = wave * 64 + nt * 16 + l16;
                C[(size_t)row * 256 + col] = acc[mt][nt][rg];
            }
        }
}

// ============ layer2 epilogue: h2 = relu(norm(agg2 + r2 + b2)), f32, width 128 ===

__global__ __launch_bounds__(256) void k_combine128(const float* __restrict__ agg2,
        const float* __restrict__ C2, const float* __restrict__ b2,
        float* __restrict__ h2) {
    int tid = blockIdx.x * 256 + threadIdx.x;
    int row = tid >> 5, l = tid & 31;
    if (row >= NN) return;
    float4 a = *(const float4*)&agg2[(size_t)row * 128 + l * 4];
    float4 r = *(const float4*)&C2[(size_t)row * 256 + 128 + l * 4];
    float4 b = *(const float4*)&b2[l * 4];
    float v0 = a.x + r.x + b.x;
    float v1 = a.y + r.y + b.y;
    float v2 = a.z + r.z + b.z;
    float v3 = a.w + r.w + b.w;
    float s = v0 * v0 + v1 * v1 + v2 * v2 + v3 * v3;
    #pragma unroll
    for (int off = 16; off > 0; off >>= 1) s += __shfl_xor(s, off, 64);
    float invn = 1.0f / fmaxf(sqrtf(s), 1e-12f);
    float4 o;
    o.x = fmaxf(v0 * invn, 0.f); o.y = fmaxf(v1 * invn, 0.f);
    o.z = fmaxf(v2 * invn, 0.f); o.w = fmaxf(v3 * invn, 0.f);
    *(float4*)&h2[(size_t)row * 128 + l * 4] = o;
}

// ================= layer 3 (f32) =================

__global__ __launch_bounds__(256) void k_q3(const float* __restrict__ h2,
        const float* __restrict__ W3l, float* __restrict__ q3) {
    __shared__ float sw[256];
    int t = threadIdx.x;
    sw[t] = W3l[t];
    __syncthreads();
    int i = blockIdx.x * 256 + t;
    if (i >= NN) return;
    const float4* row = (const float4*)(h2 + (size_t)i * 128);
    float a0 = 0.f, a1 = 0.f;
    #pragma unroll
    for (int q = 0; q < 32; q++) {
        float4 v = row[q];
        a0 += v.x * sw[4*q] + v.y * sw[4*q+1] + v.z * sw[4*q+2] + v.w * sw[4*q+3];
        a1 += v.x * sw[128+4*q] + v.y * sw[129+4*q] + v.z * sw[130+4*q] + v.w * sw[131+4*q];
    }
    q3[2 * i] = a0;
    q3[2 * i + 1] = a1;
}

__global__ __launch_bounds__(256) void k_final(const float* __restrict__ h2,
        const float* __restrict__ W3r, const float* __restrict__ b3,
        const float* __restrict__ aggq, float* __restrict__ out) {
    __shared__ float sw[256];
    int t = threadIdx.x;
    sw[t] = W3r[t];
    __syncthreads();
    int i = blockIdx.x * 256 + t;
    if (i >= NN) return;
    const float4* row = (const float4*)(h2 + (size_t)i * 128);
    float a0 = 0.f, a1 = 0.f;
    #pragma unroll
    for (int q = 0; q < 32; q++) {
        float4 v = row[q];
        a0 += v.x * sw[4*q] + v.y * sw[4*q+1] + v.z * sw[4*q+2] + v.w * sw[4*q+3];
        a1 += v.x * sw[128+4*q] + v.y * sw[129+4*q] + v.z * sw[130+4*q] + v.w * sw[131+4*q];
    }
    float v0 = aggq[2 * i] + a0 + b3[0];
    float v1 = aggq[2 * i + 1] + a1 + b3[1];
    float invn = 1.0f / fmaxf(sqrtf(v0 * v0 + v1 * v1), 1e-12f);
    v0 *= invn; v1 *= invn;
    float mx = fmaxf(v0, v1);
    float l = logf(expf(v0 - mx) + expf(v1 - mx));
    out[2 * i] = v0 - mx - l;
    out[2 * i + 1] = v1 - mx - l;
}

// ================= launch =================

extern "C" void kernel_launch(void* const* d_in, const int* in_sizes, int n_in,
                              void* d_out, int out_size, void* d_ws, size_t ws_size,
                              hipStream_t stream) {
    const float* x   = (const float*)d_in[0];
    const int*   ei  = (const int*)d_in[1];
    const float* W1l = (const float*)d_in[2];
    const float* W1r = (const float*)d_in[3];
    const float* b1  = (const float*)d_in[4];
    const float* W2l = (const float*)d_in[5];
    const float* W2r = (const float*)d_in[6];
    const float* b2  = (const float*)d_in[7];
    const float* W3l = (const float*)d_in[8];
    const float* W3r = (const float*)d_in[9];
    const float* b3  = (const float*)d_in[10];
    float* out = (float*)d_out;
    const int* src = ei;
    const int* dst = ei + NE;

    // ---- workspace layout (~262 MB) ----
    int* deg    = (int*)d_ws;                     // 102400
    int* rowptr = deg + 102400;
    int* cursor = rowptr + 102400;
    int* csr    = cursor + 102400;                // 655360
    bf16_t* W1h = (bf16_t*)(csr + 655360);        // 65536 bf16 each
    bf16_t* W1lo = W1h + 65536;
    bf16_t* W2h  = W1lo + 65536;
    bf16_t* W2lo = W2h + 65536;
    float* aggA = (float*)(W2lo + 65536);         // 12.8M f32 (reused as agg2)
    float* h1   = aggA + 12800000;                // MPAD*256 f32 (reused as h2)
    float* C2   = h1 + (size_t)MPAD * 256;        // MPAD*256 f32
    float* q3   = C2 + (size_t)MPAD * 256;        // 200000
    float* aggq = q3 + 200000;                    // 200000
    float* h2   = h1;                             // reuse after L2 GEMM consumed h1

    // ---- CSR build ----
    hipMemsetAsync(deg, 0, NN * sizeof(int), stream);
    k_hist<<<(NE + 255) / 256, 256, 0, stream>>>(dst, deg);
    k_scan<<<1, 1024, 0, stream>>>(deg, rowptr, cursor);
    k_fill<<<(NE + 255) / 256, 256, 0, stream>>>(src, dst, cursor, csr);

    // ---- weight split ----
    k_split_w1<<<256, 256, 0, stream>>>(W1l, W1r, W1h, W1lo);
    k_split_w2<<<256, 256, 0, stream>>>(W2l, W2r, W2h, W2lo);

    // ---- layer 1: agg = mean(x[nbrs]); h1 = relu(norm([agg|x] @ W1cat^T + b1)) ----
    k_gather128s<<<(NN * 32 + 255) / 256, 256, 0, stream>>>(x, 128, rowptr, csr, aggA, 128);
    k_gemm_l1<<<MPAD / 64, 256, 0, stream>>>(aggA, x, W1h, W1lo, b1, h1);

    // ---- layer 2: C2 = h1 @ [W2l;W2r]^T; agg2 = mean(p2); h2 = relu(norm(agg2+r2+b2)) ----
    k_gemm_l2<<<MPAD / 64, 256, 0, stream>>>(h1, W2h, W2lo, C2);
    k_gather128s<<<(NN * 32 + 255) / 256, 256, 0, stream>>>(C2, 256, rowptr, csr, aggA, 128);
    k_combine128<<<(NN * 32 + 255) / 256, 256, 0, stream>>>(aggA, C2, b2, h2);

    // ---- layer 3 ----
    k_q3<<<(NN + 255) / 256, 256, 0, stream>>>(h2, W3l, q3);
    k_gather2<<<(NN + 255) / 256, 256, 0, stream>>>(q3, rowptr, csr, aggq);
    k_final<<<(NN + 255) / 256, 256, 0, stream>>>(h2, W3r, b3, aggq, out);
}

// Round 5
// 455.972 us; speedup vs baseline: 6.1548x; 1.2026x over previous
//
#include <hip/hip_runtime.h>
#include <math.h>

#define NN 100000
#define NE 640000
#define MPAD 100032   // NN rounded up to 64
#define NBLK 98       // ceil(NN / 1024)

typedef __bf16 bf16_t;
typedef bf16_t bf16x8 __attribute__((ext_vector_type(8)));
typedef float  f32x4  __attribute__((ext_vector_type(4)));

// ================= CSR build =================

__global__ __launch_bounds__(256) void k_hist(const int* __restrict__ dst,
                                              int* __restrict__ deg) {
    int e = blockIdx.x * 256 + threadIdx.x;
    if (e < NE) atomicAdd(&deg[dst[e]], 1);
}

// block-level sums of deg (1024 elems per block)
__global__ __launch_bounds__(1024) void k_bsum(const int* __restrict__ deg,
                                               int* __restrict__ bsum) {
    __shared__ int warr[16];
    int t = threadIdx.x;
    int i = blockIdx.x * 1024 + t;
    int v = (i < NN) ? deg[i] : 0;
    int lane = t & 63, wid = t >> 6;
    #pragma unroll
    for (int off = 32; off > 0; off >>= 1) v += __shfl_xor(v, off, 64);
    if (lane == 0) warr[wid] = v;
    __syncthreads();
    if (t < 16) {
        int s = warr[t];
        #pragma unroll
        for (int off = 8; off > 0; off >>= 1) s += __shfl_xor(s, off, 64);
        if (t == 0) bsum[blockIdx.x] = s;
    }
}

// one wave scans NBLK block sums -> exclusive offsets
__global__ __launch_bounds__(64) void k_bscan(const int* __restrict__ bsum,
        int* __restrict__ boff, int* __restrict__ rowptr) {
    int lane = threadIdx.x;
    int carry = 0;
    for (int base = 0; base < NBLK; base += 64) {
        int i = base + lane;
        int v = (i < NBLK) ? bsum[i] : 0;
        int s = v;
        #pragma unroll
        for (int off = 1; off < 64; off <<= 1) {
            int u = __shfl_up(s, off, 64);
            if (lane >= off) s += u;
        }
        if (i < NBLK) boff[i] = carry + s - v;
        carry += __shfl(s, 63, 64);
    }
    if (lane == 0) rowptr[NN] = NE;
}

// per-block scan + global offset -> rowptr / cursor
__global__ __launch_bounds__(1024) void k_scan2(const int* __restrict__ deg,
        const int* __restrict__ boff, int* __restrict__ rowptr,
        int* __restrict__ cursor) {
    __shared__ int wsum[16];
    __shared__ int woff[16];
    int t = threadIdx.x;
    int lane = t & 63, wid = t >> 6;
    int i = blockIdx.x * 1024 + t;
    int v = (i < NN) ? deg[i] : 0;
    int s = v;
    #pragma unroll
    for (int off = 1; off < 64; off <<= 1) {
        int u = __shfl_up(s, off, 64);
        if (lane >= off) s += u;
    }
    if (lane == 63) wsum[wid] = s;
    __syncthreads();
    if (wid == 0) {
        int ws = (lane < 16) ? wsum[lane] : 0;
        #pragma unroll
        for (int off = 1; off < 16; off <<= 1) {
            int u = __shfl_up(ws, off, 64);
            if (lane >= off) ws += u;
        }
        if (lane < 16) woff[lane] = ws;
    }
    __syncthreads();
    if (i < NN) {
        int excl = boff[blockIdx.x] + (s - v) + (wid ? woff[wid - 1] : 0);
        rowptr[i] = excl;
        cursor[i] = excl;
    }
}

__global__ __launch_bounds__(256) void k_fill(const int* __restrict__ src,
        const int* __restrict__ dst, int* __restrict__ cursor,
        int* __restrict__ csr) {
    int e = blockIdx.x * 256 + threadIdx.x;
    if (e >= NE) return;
    int p = atomicAdd(&cursor[dst[e]], 1);
    csr[p] = src[e];
}

// ================= weight split (f32 -> hi/lo bf16) =================

__global__ __launch_bounds__(256) void k_split_w1(const float* __restrict__ W1l,
        const float* __restrict__ W1r, bf16_t* __restrict__ Wh,
        bf16_t* __restrict__ Wl) {
    int j = blockIdx.x, t = threadIdx.x;
    float f = (t < 128) ? W1l[j * 128 + t] : W1r[j * 128 + (t - 128)];
    bf16_t h = (bf16_t)f;
    bf16_t l = (bf16_t)(f - (float)h);
    Wh[j * 256 + t] = h;
    Wl[j * 256 + t] = l;
}

__global__ __launch_bounds__(256) void k_split_w2(const float* __restrict__ W2l,
        const float* __restrict__ W2r, bf16_t* __restrict__ Wh,
        bf16_t* __restrict__ Wl) {
    int j = blockIdx.x, t = threadIdx.x;
    float f = (j < 128) ? W2l[j * 256 + t] : W2r[(j - 128) * 256 + t];
    bf16_t h = (bf16_t)f;
    bf16_t l = (bf16_t)(f - (float)h);
    Wh[j * 256 + t] = h;
    Wl[j * 256 + t] = l;
}

// ================= gather-mean (f32, 128 wide, strided) =================

__global__ __launch_bounds__(256) void k_gather128s(const float* __restrict__ feat,
        int fstride, const int* __restrict__ rowptr, const int* __restrict__ csr,
        float* __restrict__ agg, int astride) {
    int tid = blockIdx.x * 256 + threadIdx.x;
    int node = tid >> 5;
    if (node >= NN) return;
    int lane4 = (tid & 31) << 2;
    int beg = rowptr[node], end = rowptr[node + 1];
    float4 acc = make_float4(0.f, 0.f, 0.f, 0.f);
    int e = beg;
    for (; e + 1 < end; e += 2) {
        int s0 = csr[e], s1 = csr[e + 1];
        float4 v0 = *(const float4*)(feat + (size_t)s0 * fstride + lane4);
        float4 v1 = *(const float4*)(feat + (size_t)s1 * fstride + lane4);
        acc.x += v0.x + v1.x; acc.y += v0.y + v1.y;
        acc.z += v0.z + v1.z; acc.w += v0.w + v1.w;
    }
    if (e < end) {
        int s0 = csr[e];
        float4 v0 = *(const float4*)(feat + (size_t)s0 * fstride + lane4);
        acc.x += v0.x; acc.y += v0.y; acc.z += v0.z; acc.w += v0.w;
    }
    float iv = 1.0f / (float)max(end - beg, 1);
    acc.x *= iv; acc.y *= iv; acc.z *= iv; acc.w *= iv;
    *(float4*)(agg + (size_t)node * astride + lane4) = acc;
}

// 2-wide gather-mean (layer 3)
__global__ __launch_bounds__(256) void k_gather2(const float* __restrict__ feat,
        const int* __restrict__ rowptr, const int* __restrict__ csr,
        float* __restrict__ agg) {
    int n = blockIdx.x * 256 + threadIdx.x;
    if (n >= NN) return;
    int beg = rowptr[n], end = rowptr[n + 1];
    float a0 = 0.f, a1 = 0.f;
    for (int e = beg; e < end; e++) {
        int s = csr[e];
        a0 += feat[2 * s];
        a1 += feat[2 * s + 1];
    }
    float iv = 1.0f / (float)max(end - beg, 1);
    agg[2 * n] = a0 * iv;
    agg[2 * n + 1] = a1 * iv;
}

// ================= split-bf16 MFMA GEMM =================
// C = A @ W^T with A,W f32 emulated as hi+lo bf16: C ~= Ah*Wh + Al*Wh + Ah*Wl
// block 256 = 4 waves; BM=64, BN=256 (wave owns 64 cols), BK=32.
// frag layouts (HW-verified m89/m120): A/B lane = [idx=lane&15][k=quad*8+j];
// C/D: col=lane&15, row=quad*4+reg.

#define PADK 8

__device__ __forceinline__ void split8(const float* __restrict__ p,
                                       bf16x8& h, bf16x8& l) {
    float4 v0 = *(const float4*)p;
    float4 v1 = *(const float4*)(p + 4);
    float f[8] = {v0.x, v0.y, v0.z, v0.w, v1.x, v1.y, v1.z, v1.w};
    #pragma unroll
    for (int i = 0; i < 8; i++) {
        bf16_t hi = (bf16_t)f[i];
        h[i] = hi;
        l[i] = (bf16_t)(f[i] - (float)hi);
    }
}

// Layer-1 GEMM, A = [agg | x]; fused epilogue h1 = relu(l2norm(C + b1))
__global__ __launch_bounds__(256) void k_gemm_l1(const float* __restrict__ Aa,
        const float* __restrict__ Ax, const bf16_t* __restrict__ Wh,
        const bf16_t* __restrict__ Wl, const float* __restrict__ bias,
        float* __restrict__ H) {
    __shared__ bf16_t sAh[64][32 + PADK], sAl[64][32 + PADK];
    __shared__ bf16_t sWh[256][32 + PADK], sWl[256][32 + PADK];
    __shared__ float pr[64][4];
    int t = threadIdx.x;
    int wave = t >> 6, lane = t & 63, quad = lane >> 4, l16 = lane & 15;
    int r0 = blockIdx.x * 64;
    f32x4 acc[4][4] = {};
    int arow = t >> 2, aseg = t & 3;
    int grow = r0 + arow; if (grow >= NN) grow = NN - 1;
    for (int k0 = 0; k0 < 256; k0 += 32) {
        const float* Asrc = (k0 < 128) ? Aa : Ax;
        int kb = (k0 < 128) ? k0 : (k0 - 128);
        bf16x8 h8, l8;
        split8(&Asrc[(size_t)grow * 128 + kb + aseg * 8], h8, l8);
        *(bf16x8*)&sAh[arow][aseg * 8] = h8;
        *(bf16x8*)&sAl[arow][aseg * 8] = l8;
        #pragma unroll
        for (int i = 0; i < 4; i++) {
            int wr = arow + i * 64;
            *(bf16x8*)&sWh[wr][aseg * 8] = *(const bf16x8*)&Wh[(size_t)wr * 256 + k0 + aseg * 8];
            *(bf16x8*)&sWl[wr][aseg * 8] = *(const bf16x8*)&Wl[(size_t)wr * 256 + k0 + aseg * 8];
        }
        __syncthreads();
        bf16x8 ah[4], al[4], bh[4], bl[4];
        #pragma unroll
        for (int mt = 0; mt < 4; mt++) {
            ah[mt] = *(bf16x8*)&sAh[mt * 16 + l16][quad * 8];
            al[mt] = *(bf16x8*)&sAl[mt * 16 + l16][quad * 8];
        }
        #pragma unroll
        for (int nt = 0; nt < 4; nt++) {
            bh[nt] = *(bf16x8*)&sWh[wave * 64 + nt * 16 + l16][quad * 8];
            bl[nt] = *(bf16x8*)&sWl[wave * 64 + nt * 16 + l16][quad * 8];
        }
        #pragma unroll
        for (int mt = 0; mt < 4; mt++)
            #pragma unroll
            for (int nt = 0; nt < 4; nt++) {
                acc[mt][nt] = __builtin_amdgcn_mfma_f32_16x16x32_bf16(ah[mt], bh[nt], acc[mt][nt], 0, 0, 0);
                acc[mt][nt] = __builtin_amdgcn_mfma_f32_16x16x32_bf16(al[mt], bh[nt], acc[mt][nt], 0, 0, 0);
                acc[mt][nt] = __builtin_amdgcn_mfma_f32_16x16x32_bf16(ah[mt], bl[nt], acc[mt][nt], 0, 0, 0);
            }
        __syncthreads();
    }
    float bcol[4];
    #pragma unroll
    for (int nt = 0; nt < 4; nt++) bcol[nt] = bias[wave * 64 + nt * 16 + l16];
    #pragma unroll
    for (int mt = 0; mt < 4; mt++)
        #pragma unroll
        for (int nt = 0; nt < 4; nt++)
            #pragma unroll
            for (int rg = 0; rg < 4; rg++)
                acc[mt][nt][rg] += bcol[nt];
    float ss[4][4];
    #pragma unroll
    for (int mt = 0; mt < 4; mt++)
        #pragma unroll
        for (int rg = 0; rg < 4; rg++) {
            float s = 0.f;
            #pragma unroll
            for (int nt = 0; nt < 4; nt++) s += acc[mt][nt][rg] * acc[mt][nt][rg];
            #pragma unroll
            for (int off = 1; off < 16; off <<= 1) s += __shfl_xor(s, off, 64);
            ss[mt][rg] = s;
        }
    if (l16 == 0) {
        #pragma unroll
        for (int mt = 0; mt < 4; mt++)
            #pragma unroll
            for (int rg = 0; rg < 4; rg++)
                pr[mt * 16 + quad * 4 + rg][wave] = ss[mt][rg];
    }
    __syncthreads();
    #pragma unroll
    for (int mt = 0; mt < 4; mt++)
        #pragma unroll
        for (int rg = 0; rg < 4; rg++) {
            int lr = mt * 16 + quad * 4 + rg;
            int row = r0 + lr;
            if (row >= NN) continue;
            float tot = pr[lr][0] + pr[lr][1] + pr[lr][2] + pr[lr][3];
            float inv = 1.0f / fmaxf(sqrtf(tot), 1e-12f);
            #pragma unroll
            for (int nt = 0; nt < 4; nt++) {
                int col = wave * 64 + nt * 16 + l16;
                H[(size_t)row * 256 + col] = fmaxf(acc[mt][nt][rg] * inv, 0.f);
            }
        }
}

// Layer-2 GEMM: C2 = h1 @ [W2l;W2r]^T, plain f32 store
__global__ __launch_bounds__(256) void k_gemm_l2(const float* __restrict__ A,
        const bf16_t* __restrict__ Wh, const bf16_t* __restrict__ Wl,
        float* __restrict__ C) {
    __shared__ bf16_t sAh[64][32 + PADK], sAl[64][32 + PADK];
    __shared__ bf16_t sWh[256][32 + PADK], sWl[256][32 + PADK];
    int t = threadIdx.x;
    int wave = t >> 6, lane = t & 63, quad = lane >> 4, l16 = lane & 15;
    int r0 = blockIdx.x * 64;
    f32x4 acc[4][4] = {};
    int arow = t >> 2, aseg = t & 3;
    int grow = r0 + arow; if (grow >= NN) grow = NN - 1;
    for (int k0 = 0; k0 < 256; k0 += 32) {
        bf16x8 h8, l8;
        split8(&A[(size_t)grow * 256 + k0 + aseg * 8], h8, l8);
        *(bf16x8*)&sAh[arow][aseg * 8] = h8;
        *(bf16x8*)&sAl[arow][aseg * 8] = l8;
        #pragma unroll
        for (int i = 0; i < 4; i++) {
            int wr = arow + i * 64;
            *(bf16x8*)&sWh[wr][aseg * 8] = *(const bf16x8*)&Wh[(size_t)wr * 256 + k0 + aseg * 8];
            *(bf16x8*)&sWl[wr][aseg * 8] = *(const bf16x8*)&Wl[(size_t)wr * 256 + k0 + aseg * 8];
        }
        __syncthreads();
        bf16x8 ah[4], al[4], bh[4], bl[4];
        #pragma unroll
        for (int mt = 0; mt < 4; mt++) {
            ah[mt] = *(bf16x8*)&sAh[mt * 16 + l16][quad * 8];
            al[mt] = *(bf16x8*)&sAl[mt * 16 + l16][quad * 8];
        }
        #pragma unroll
        for (int nt = 0; nt < 4; nt++) {
            bh[nt] = *(bf16x8*)&sWh[wave * 64 + nt * 16 + l16][quad * 8];
            bl[nt] = *(bf16x8*)&sWl[wave * 64 + nt * 16 + l16][quad * 8];
        }
        #pragma unroll
        for (int mt = 0; mt < 4; mt++)
            #pragma unroll
            for (int nt = 0; nt < 4; nt++) {
                acc[mt][nt] = __builtin_amdgcn_mfma_f32_16x16x32_bf16(ah[mt], bh[nt], acc[mt][nt], 0, 0, 0);
                acc[mt][nt] = __builtin_amdgcn_mfma_f32_16x16x32_bf16(al[mt], bh[nt], acc[mt][nt], 0, 0, 0);
                acc[mt][nt] = __builtin_amdgcn_mfma_f32_16x16x32_bf16(ah[mt], bl[nt], acc[mt][nt], 0, 0, 0);
            }
        __syncthreads();
    }
    #pragma unroll
    for (int mt = 0; mt < 4; mt++)
        #pragma unroll
        for (int rg = 0; rg < 4; rg++) {
            int row = r0 + mt * 16 + quad * 4 + rg;
            if (row >= NN) continue;
            #pragma unroll
            for (int nt = 0; nt < 4; nt++) {
                int col = wave * 64 + nt * 16 + l16;
                C[(size_t)row * 256 + col] = acc[mt][nt][rg];
            }
        }
}

// ==== layer2 epilogue + fused q3: h2 = relu(norm(agg2+r2+b2)); q3 = h2 @ W3l^T ===
// half-wave (32 lanes) per row; lane covers 4 elems of the 128-wide row

__global__ __launch_bounds__(256) void k_combine128(const float* __restrict__ agg2,
        const float* __restrict__ C2, const float* __restrict__ b2,
        const float* __restrict__ W3l, float* __restrict__ h2,
        float* __restrict__ q3) {
    __shared__ float sw[256];
    int t = threadIdx.x;
    sw[t] = W3l[t];
    __syncthreads();
    int tid = blockIdx.x * 256 + t;
    int row = tid >> 5, l = tid & 31;
    if (row >= NN) return;
    float4 a = *(const float4*)&agg2[(size_t)row * 128 + l * 4];
    float4 r = *(const float4*)&C2[(size_t)row * 256 + 128 + l * 4];
    float4 b = *(const float4*)&b2[l * 4];
    float v0 = a.x + r.x + b.x;
    float v1 = a.y + r.y + b.y;
    float v2 = a.z + r.z + b.z;
    float v3 = a.w + r.w + b.w;
    float s = v0 * v0 + v1 * v1 + v2 * v2 + v3 * v3;
    #pragma unroll
    for (int off = 16; off > 0; off >>= 1) s += __shfl_xor(s, off, 64);
    float invn = 1.0f / fmaxf(sqrtf(s), 1e-12f);
    float4 o;
    o.x = fmaxf(v0 * invn, 0.f); o.y = fmaxf(v1 * invn, 0.f);
    o.z = fmaxf(v2 * invn, 0.f); o.w = fmaxf(v3 * invn, 0.f);
    *(float4*)&h2[(size_t)row * 128 + l * 4] = o;
    // fused q3 = h2row @ W3l^T (2 outputs)
    float a0 = o.x * sw[l*4] + o.y * sw[l*4+1] + o.z * sw[l*4+2] + o.w * sw[l*4+3];
    float a1 = o.x * sw[128+l*4] + o.y * sw[129+l*4] + o.z * sw[130+l*4] + o.w * sw[131+l*4];
    #pragma unroll
    for (int off = 16; off > 0; off >>= 1) {
        a0 += __shfl_xor(a0, off, 64);
        a1 += __shfl_xor(a1, off, 64);
    }
    if (l == 0) {
        q3[2 * row] = a0;
        q3[2 * row + 1] = a1;
    }
}

// ================= final =================

__global__ __launch_bounds__(256) void k_final(const float* __restrict__ h2,
        const float* __restrict__ W3r, const float* __restrict__ b3,
        const float* __restrict__ aggq, float* __restrict__ out) {
    __shared__ float sw[256];
    int t = threadIdx.x;
    sw[t] = W3r[t];
    __syncthreads();
    int i = blockIdx.x * 256 + t;
    if (i >= NN) return;
    const float4* row = (const float4*)(h2 + (size_t)i * 128);
    float a0 = 0.f, a1 = 0.f;
    #pragma unroll
    for (int q = 0; q < 32; q++) {
        float4 v = row[q];
        a0 += v.x * sw[4*q] + v.y * sw[4*q+1] + v.z * sw[4*q+2] + v.w * sw[4*q+3];
        a1 += v.x * sw[128+4*q] + v.y * sw[129+4*q] + v.z * sw[130+4*q] + v.w * sw[131+4*q];
    }
    float v0 = aggq[2 * i] + a0 + b3[0];
    float v1 = aggq[2 * i + 1] + a1 + b3[1];
    float invn = 1.0f / fmaxf(sqrtf(v0 * v0 + v1 * v1), 1e-12f);
    v0 *= invn; v1 *= invn;
    float mx = fmaxf(v0, v1);
    float l = logf(expf(v0 - mx) + expf(v1 - mx));
    out[2 * i] = v0 - mx - l;
    out[2 * i + 1] = v1 - mx - l;
}

// ================= launch =================

extern "C" void kernel_launch(void* const* d_in, const int* in_sizes, int n_in,
                              void* d_out, int out_size, void* d_ws, size_t ws_size,
                              hipStream_t stream) {
    const float* x   = (const float*)d_in[0];
    const int*   ei  = (const int*)d_in[1];
    const float* W1l = (const float*)d_in[2];
    const float* W1r = (const float*)d_in[3];
    const float* b1  = (const float*)d_in[4];
    const float* W2l = (const float*)d_in[5];
    const float* W2r = (const float*)d_in[6];
    const float* b2  = (const float*)d_in[7];
    const float* W3l = (const float*)d_in[8];
    const float* W3r = (const float*)d_in[9];
    const float* b3  = (const float*)d_in[10];
    float* out = (float*)d_out;
    const int* src = ei;
    const int* dst = ei + NE;

    // ---- workspace layout ----
    int* deg    = (int*)d_ws;                     // 102400
    int* rowptr = deg + 102400;
    int* cursor = rowptr + 102400;
    int* csr    = cursor + 102400;                // 655360
    int* bsum   = csr + 655360;                   // 128
    int* boff   = bsum + 128;                     // 128
    bf16_t* W1h  = (bf16_t*)(boff + 128);         // 65536 bf16 each
    bf16_t* W1lo = W1h + 65536;
    bf16_t* W2h  = W1lo + 65536;
    bf16_t* W2lo = W2h + 65536;
    float* aggA = (float*)(W2lo + 65536);         // 12.8M f32 (reused as agg2)
    float* h1   = aggA + 12800000;                // MPAD*256 f32 (reused as h2)
    float* C2   = h1 + (size_t)MPAD * 256;        // MPAD*256 f32
    float* q3   = C2 + (size_t)MPAD * 256;        // 200000
    float* aggq = q3 + 200000;                    // 200000
    float* h2   = h1;                             // reuse after L2 GEMM consumed h1

    // ---- CSR build (multi-block scan) ----
    hipMemsetAsync(deg, 0, NN * sizeof(int), stream);
    k_hist<<<(NE + 255) / 256, 256, 0, stream>>>(dst, deg);
    k_bsum<<<NBLK, 1024, 0, stream>>>(deg, bsum);
    k_bscan<<<1, 64, 0, stream>>>(bsum, boff, rowptr);
    k_scan2<<<NBLK, 1024, 0, stream>>>(deg, boff, rowptr, cursor);
    k_fill<<<(NE + 255) / 256, 256, 0, stream>>>(src, dst, cursor, csr);

    // ---- weight split ----
    k_split_w1<<<256, 256, 0, stream>>>(W1l, W1r, W1h, W1lo);
    k_split_w2<<<256, 256, 0, stream>>>(W2l, W2r, W2h, W2lo);

    // ---- layer 1 ----
    k_gather128s<<<(NN * 32 + 255) / 256, 256, 0, stream>>>(x, 128, rowptr, csr, aggA, 128);
    k_gemm_l1<<<MPAD / 64, 256, 0, stream>>>(aggA, x, W1h, W1lo, b1, h1);

    // ---- layer 2 ----
    k_gemm_l2<<<MPAD / 64, 256, 0, stream>>>(h1, W2h, W2lo, C2);
    k_gather128s<<<(NN * 32 + 255) / 256, 256, 0, stream>>>(C2, 256, rowptr, csr, aggA, 128);
    k_combine128<<<(NN * 32 + 255) / 256, 256, 0, stream>>>(aggA, C2, b2, W3l, h2, q3);

    // ---- layer 3 ----
    k_gather2<<<(NN + 255) / 256, 256, 0, stream>>>(q3, rowptr, csr, aggq);
    k_final<<<(NN + 255) / 256, 256, 0, stream>>>(h2, W3r, b3, aggq, out);
}